// Round 6
// baseline (616.962 us; speedup 1.0000x reference)
//
#include <hip/hip_runtime.h>
#include <hip/hip_fp16.h>
#include <cstddef>

// ---------------------------------------------------------------------------
// SpatialAudioRenderer on MI355X — v16: unthrottle the latency-bound small
// kernels. v15: 603us with conv2-family at ~130-135 each; the unexplained
// ~100-150us is xcorr_stats/mix_xcorr running at 25% occupancy with long
// serial per-thread chains. v16: XCH 2048->1024 (grid x2, per-thread work
// /2), float4 staging, mix computed from LDS (no bounds branches inner).
// conv2 kernels byte-identical to v15.
// ---------------------------------------------------------------------------

#define TLEN 131072
#define NB 8
#define NICH 2
#define NHID 64
#define NH2 128
#define EPSV 1e-5f
#define CNTF 1048576.0f  // NB * TLEN
#define FT 120           // final-kernel output tile
#define FGRID 1093       // ceil(TLEN / FT)
#define XCH 1024         // xcorr t-chunk (v16: was 2048)
#define NCH 128          // TLEN / XCH
#define XGRID 1024       // NB * NCH

typedef _Float16 f16x8 __attribute__((ext_vector_type(8)));
typedef float f32x4 __attribute__((ext_vector_type(4)));

__device__ __forceinline__ float lrelu(float v) { return fmaxf(v, 0.2f * v); }
__device__ __forceinline__ unsigned short h16(float v) {
  return __half_as_ushort(__float2half(v));
}
__device__ __forceinline__ float fh16(unsigned short u) {
  return __half2float(__ushort_as_half(u));
}
// fast tanh for the OUTPUT path only (error ~1e-6; correct +/-1 limits).
__device__ __forceinline__ float ftanh(float x) {
  float e = __expf(2.f * x);
  return 1.f - 2.f / (e + 1.f);
}

// ---------------------------------------------------------------------------
// Kernel 0: weight prep.
//  w2sp/w2re: fragment-contiguous conv2 A (v8 layout).
//  w3g:       conv3 A' [c*512 + m*32 + ch%32].
//  w1sp/w1re: conv1 A, frag m: [m*512 + mn*32 + (i*16+kk)], kk<7 valid.
// ---------------------------------------------------------------------------
__global__ __launch_bounds__(256) void prep_weights(
    const float* __restrict__ W2c, const float* __restrict__ RW2c,
    const float* __restrict__ RW3c,
    const float* __restrict__ W1c, const float* __restrict__ RW1c,
    unsigned short* __restrict__ w2sp, unsigned short* __restrict__ w2re,
    unsigned short* __restrict__ w3g,
    unsigned short* __restrict__ w1sp, unsigned short* __restrict__ w1re)
{
  int e = blockIdx.x * 256 + threadIdx.x;
  if (e < 114688) {
    int e2 = (e >= 57344) ? e - 57344 : e;
    int frag = e2 >> 9, within = e2 & 511;
    int c = frag >> 3, mt = frag & 7;
    int mn = within >> 5, kk = within & 31;
    int o = mt * 16 + mn;
    int tap = c >> 1, ch = (c & 1) * 32 + kk;
    const float* src = (e >= 57344) ? RW2c : W2c;
    unsigned short* dst = (e >= 57344) ? w2re : w2sp;
    dst[e2] = h16(src[(o * 64 + ch) * 7 + tap]);
  } else if (e < 116736) {
    int e2 = e - 114688;
    int c = e2 >> 9, within = e2 & 511;
    int m = within >> 5, kk = within & 31;
    int ch = c * 32 + kk;
    w3g[e2] = (m < 14) ? h16(RW3c[((m / 7) * 128 + ch) * 7 + (m % 7)])
                       : (unsigned short)0;
  } else if (e < 120832) {
    int e2 = e - 116736;
    int which = (e2 >= 2048);
    int e3 = e2 & 2047;
    int m = e3 >> 9, w = e3 & 511;
    int mn = w >> 5, K = w & 31;
    int i = K >> 4, kk = K & 15;
    const float* src = which ? RW1c : W1c;
    unsigned short* dst = which ? w1re : w1sp;
    dst[e3] = (kk < 7) ? h16(src[(m * 16 + mn) * 14 + i * 7 + kk])
                       : (unsigned short)0;
  }
}

// ---------------------------------------------------------------------------
// Kernel A: input autocorrelation partials (30 floats/block). Spatial path.
// v16: XCH=1024, float4 staging, 4 t/thread. Grid XGRID.
// ---------------------------------------------------------------------------
__global__ __launch_bounds__(256) void xcorr_stats(
    const float* __restrict__ z, float* __restrict__ partials)
{
  const int b = blockIdx.x >> 7;
  const int t0 = (blockIdx.x & (NCH - 1)) * XCH;
  __shared__ float zs[2][XCH + 8];
  __shared__ float redx[4][30];
  #pragma unroll
  for (int i = 0; i < 2; ++i) {
    const float* zp = &z[(size_t)(b * 2 + i) * TLEN + t0];
    *(float4*)&zs[i][threadIdx.x * 4] =
        *(const float4*)&zp[threadIdx.x * 4];
    if (threadIdx.x < 7) {
      int tg = t0 + XCH + threadIdx.x;
      zs[i][XCH + threadIdx.x] =
          (tg < TLEN) ? z[(size_t)(b * 2 + i) * TLEN + tg] : 0.f;
    }
    if (threadIdx.x == 7) zs[i][XCH + 7] = 0.f;
  }
  __syncthreads();

  float acc[30];
  #pragma unroll
  for (int q = 0; q < 30; ++q) acc[q] = 0.f;
  const int tb = threadIdx.x * 4;
  #pragma unroll
  for (int tt = 0; tt < 4; ++tt) {
    int j = tb + tt;
    float z0 = zs[0][j], z1 = zs[1][j];
    acc[28] += z0; acc[29] += z1;
    #pragma unroll
    for (int d = 0; d < 7; ++d) {
      float a0 = zs[0][j + d], a1 = zs[1][j + d];
      acc[d]      += z0 * a0;
      acc[7 + d]  += z0 * a1;
      acc[14 + d] += z1 * a0;
      acc[21 + d] += z1 * a1;
    }
  }
  #pragma unroll
  for (int q = 0; q < 30; ++q)
    #pragma unroll
    for (int m = 1; m <= 32; m <<= 1)
      acc[q] += __shfl_xor(acc[q], m, 64);
  const int lane = threadIdx.x & 63, wv = threadIdx.x >> 6;
  if (lane == 0)
    #pragma unroll
    for (int q = 0; q < 30; ++q) redx[wv][q] = acc[q];
  __syncthreads();
  if (threadIdx.x < 30)
    partials[blockIdx.x * 30 + threadIdx.x] =
        redx[0][threadIdx.x] + redx[1][threadIdx.x] +
        redx[2][threadIdx.x] + redx[3][threadIdx.x];
}

// ---------------------------------------------------------------------------
// Kernel B: assemble coef1 from Rx/A1 (parallel reduction: 8 chunks x 30 q).
// ---------------------------------------------------------------------------
__global__ __launch_bounds__(256) void assemble_coef1(
    const float* __restrict__ partials, int nblocks,
    const float* __restrict__ W1c, const float* __restrict__ b1c,
    const float* __restrict__ g, const float* __restrict__ be,
    float* __restrict__ coef)
{
  __shared__ float R[30];
  __shared__ float pr[8][30];
  __shared__ float w1s[64 * 14];
  for (int e = threadIdx.x; e < 64 * 14; e += 256) w1s[e] = W1c[e];
  if (threadIdx.x < 240) {
    int q = threadIdx.x % 30, chunk = threadIdx.x / 30;
    float s = 0.f;
    for (int j = chunk; j < nblocks; j += 8) s += partials[j * 30 + q];
    pr[chunk][q] = s;
  }
  __syncthreads();
  if (threadIdx.x < 30) {
    float s = 0.f;
    #pragma unroll
    for (int c = 0; c < 8; ++c) s += pr[c][threadIdx.x];
    R[threadIdx.x] = s;
  }
  __syncthreads();
  if (threadIdx.x < 64) {
    int o = threadIdx.x;
    const float* w = &w1s[o * 14];
    float b1v = b1c[o];
    float sy = 0.f;
    #pragma unroll
    for (int i = 0; i < 2; ++i)
      #pragma unroll
      for (int k = 0; k < 7; ++k) sy += w[i * 7 + k] * R[28 + i];
    float syy = 0.f;
    #pragma unroll
    for (int i = 0; i < 2; ++i)
      #pragma unroll
      for (int k = 0; k < 7; ++k) {
        float wv = w[i * 7 + k];
        #pragma unroll
        for (int i2 = 0; i2 < 2; ++i2)
          #pragma unroll
          for (int k2 = 0; k2 < 7; ++k2) {
            int d = k2 - k;
            float r = (d >= 0) ? R[i * 14 + i2 * 7 + d]
                               : R[i2 * 14 + i * 7 - d];
            syy += wv * w[i2 * 7 + k2] * r;
          }
      }
    float S1 = CNTF * b1v + sy;
    float S2 = 2.f * b1v * S1 - CNTF * b1v * b1v + syy;
    float mean = S1 / CNTF;
    float var = S2 / CNTF - mean * mean;
    float a = g[o] * rsqrtf(var + EPSV);
    coef[o] = a;
    coef[64 + o] = be[o] - mean * a;
  }
}

// ---------------------------------------------------------------------------
// Kernel 2: reduce conv2-stats partials -> bn affine coefs.
// Emits coef[2C+c] = d + a*b (b2 folded for the final epilogue).
// ---------------------------------------------------------------------------
__global__ __launch_bounds__(256) void reduce_coef(
    const float* __restrict__ partials, int nblocks, int C,
    const float* __restrict__ bso,
    const float* __restrict__ g, const float* __restrict__ be,
    float* __restrict__ coef)
{
  const int c = blockIdx.x;
  float s = 0.f, ss = 0.f;
  for (int j = threadIdx.x; j < nblocks; j += 256) {
    s  += partials[j * 2 * C + c];
    ss += partials[j * 2 * C + C + c];
  }
  #pragma unroll
  for (int off = 32; off >= 1; off >>= 1) {
    s  += __shfl_down(s, off, 64);
    ss += __shfl_down(ss, off, 64);
  }
  __shared__ float rs[4], rss[4];
  const int lane = threadIdx.x & 63, wv = threadIdx.x >> 6;
  if (lane == 0) { rs[wv] = s; rss[wv] = ss; }
  __syncthreads();
  if (threadIdx.x == 0) {
    float st  = rs[0] + rs[1] + rs[2] + rs[3];
    float sst = rss[0] + rss[1] + rss[2] + rss[3];
    float mean = st / CNTF;
    float var  = sst / CNTF - mean * mean;
    float a = g[c] * rsqrtf(var + EPSV);
    float d = be[c] - mean * a;
    coef[c] = a;
    coef[C + c] = d;
    coef[2 * C + c] = d + a * bso[c];
  }
}

// ---------------------------------------------------------------------------
// Shared: stage x (fp32, 168 cols) then h1 via MFMA.
// xs col j <-> t = t0 - HOF - 3 + j.  h1f row r <-> t = t0 - HOF + r.
// B tile xw[n][K=i*16+kk] = xs[i][n+kk] (kk<7), built in LDS; A from w1f.
// ---------------------------------------------------------------------------
__device__ __forceinline__ void stage_x(
    int t0, int xoff, const float* __restrict__ xin, int b, float* xs)
{
  for (int e = threadIdx.x; e < 2 * 168; e += 256) {
    int i = e / 168, j = e % 168;
    int tg = t0 - xoff + j;
    xs[e] = (tg >= 0 && tg < TLEN) ? xin[(b * NICH + i) * TLEN + tg] : 0.f;
  }
}

template<int HOF>
__device__ __forceinline__ void h1_mfma(
    int t0, const float* xs, unsigned short* xw,
    const unsigned short* __restrict__ w1f,
    const float* __restrict__ coef1, const float* __restrict__ b1c,
    unsigned short* h1f)
{
  // build im2col B tile: 144 rows x 32 halfs
  for (int e = threadIdx.x; e < 144 * 2; e += 256) {
    int n = e >> 1, i = e & 1;
    const float* xp = &xs[i * 168 + n];
    unsigned short hv[7];
    #pragma unroll
    for (int kk = 0; kk < 7; ++kk) hv[kk] = h16(xp[kk]);
    *(uint4*)(xw + n * 32 + i * 16) = make_uint4(
        hv[0] | ((unsigned)hv[1] << 16), hv[2] | ((unsigned)hv[3] << 16),
        hv[4] | ((unsigned)hv[5] << 16), (unsigned)hv[6]);
    *(uint4*)(xw + n * 32 + i * 16 + 8) = make_uint4(0, 0, 0, 0);
  }
  __syncthreads();

  const int lane = threadIdx.x & 63;
  const int wv = threadIdx.x >> 6;
  const int mn = lane & 15, quad = lane >> 4;
  f16x8 A1 = *(const f16x8*)(w1f + wv * 512 + mn * 32 + quad * 8);
  f32x4 acc1[9];
  #pragma unroll
  for (int nt = 0; nt < 9; ++nt) {
    f32x4 z = {0.f, 0.f, 0.f, 0.f};
    acc1[nt] = z;
  }
  #pragma unroll
  for (int nt = 0; nt < 9; ++nt) {
    f16x8 bb = *(const f16x8*)(xw + (nt * 16 + mn) * 32 + quad * 8);
    acc1[nt] = __builtin_amdgcn_mfma_f32_16x16x32_f16(A1, bb, acc1[nt], 0, 0, 0);
  }
  // epilogue: bn1 (b1 folded) + lrelu + OOB zero -> h1f[n][ch]
  const int ch0 = wv * 16 + quad * 4;
  float a1v[4], dd[4];
  #pragma unroll
  for (int r = 0; r < 4; ++r) {
    a1v[r] = coef1[ch0 + r];
    dd[r]  = coef1[64 + ch0 + r] + a1v[r] * b1c[ch0 + r];
  }
  #pragma unroll
  for (int nt = 0; nt < 9; ++nt) {
    int n = nt * 16 + mn;
    int t = t0 - HOF + n;
    bool ok = (t >= 0) && (t < TLEN);
    unsigned us[4];
    #pragma unroll
    for (int r = 0; r < 4; ++r) {
      float v = lrelu(a1v[r] * acc1[nt][r] + dd[r]);
      us[r] = h16(ok ? v : 0.f);
    }
    *(uint2*)(h1f + n * 72 + ch0) =
        make_uint2(us[0] | (us[1] << 16), us[2] | (us[3] << 16));
  }
}

// ---------------------------------------------------------------------------
// Kernel 3/9: conv2 via fp16 MFMA, stats (+ optional h1 save).
// 128 o x 128 t per block; v10 mapping: 2M x 8N per wave, shared B across
// waves, prefetched A. LDS 31,296 B.
// SAVE==1: flush h1f rows 3..130 (post-bn1 fp16, bit-identical to the final
// kernel's recompute) to h1out, issued BEFORE the conv2 loop so stores retire
// under MFMA (v15).
// ---------------------------------------------------------------------------
template<int SAVE>
__global__ __launch_bounds__(256, 4) void conv2_stats_mfma(
    const float* __restrict__ xin,
    const unsigned short* __restrict__ w1f, const float* __restrict__ b1c,
    const float* __restrict__ coef1,
    const unsigned short* __restrict__ w2f,
    const float* __restrict__ b2c,
    float* __restrict__ partials,
    unsigned short* __restrict__ h1out)
{
  const int b  = blockIdx.x >> 10;
  const int t0 = (blockIdx.x & 1023) * 128;

  __shared__ __align__(16) char smem[31296];
  unsigned short* h1f = (unsigned short*)smem;          // [144][72], r <-> t0-3+r
  float* xs = (float*)(smem + 20736);                   // [2][168], j <-> t0-6+j
  unsigned short* xw = (unsigned short*)(smem + 22080); // [144][32]
  float* redS = (float*)smem;                           // [128][17] (late alias)
  float* redSS= (float*)(smem + 8704);

  stage_x(t0, 6, xin, b, xs);
  __syncthreads();
  h1_mfma<3>(t0, xs, xw, w1f, coef1, b1c, h1f);
  __syncthreads();

  if (SAVE == 1) {
    // h1f stable after the barrier above; stores ride out under the conv2
    // MFMA loop below. 128 rows x 64 ch fp16, coalesced uint4.
    for (int e = threadIdx.x; e < 1024; e += 256) {
      int row = e >> 3, c8 = (e & 7) * 8;
      *(uint4*)(h1out + ((size_t)(b * TLEN + t0 + row) * 64 + c8)) =
          *(const uint4*)(h1f + (row + 3) * 72 + c8);
    }
  }

  const int lane = threadIdx.x & 63;
  const int wv = threadIdx.x >> 6;
  const int mn = lane & 15, quad = lane >> 4;

  f32x4 acc[2][8];
  #pragma unroll
  for (int mt = 0; mt < 2; ++mt)
    #pragma unroll
    for (int nt = 0; nt < 8; ++nt) {
      f32x4 z = {0.f, 0.f, 0.f, 0.f};
      acc[mt][nt] = z;
    }

  f16x8 ca[2], na[2];
  auto loadA = [&](int c, f16x8 (&A)[2]) {
    #pragma unroll
    for (int mt = 0; mt < 2; ++mt)
      A[mt] = *(const f16x8*)(w2f + (c * 8 + wv * 2 + mt) * 512 + mn * 32 + quad * 8);
  };
  loadA(0, ca);
  #pragma unroll
  for (int c = 0; c < 14; ++c) {
    if (c < 13) loadA(c + 1, na);
    const int tap = c >> 1;
    const int ch0 = (c & 1) * 32 + quad * 8;
    #pragma unroll
    for (int nt = 0; nt < 8; ++nt) {
      f16x8 bb = *(const f16x8*)(h1f + (nt * 16 + mn + tap) * 72 + ch0);
      acc[0][nt] = __builtin_amdgcn_mfma_f32_16x16x32_f16(ca[0], bb, acc[0][nt], 0, 0, 0);
      acc[1][nt] = __builtin_amdgcn_mfma_f32_16x16x32_f16(ca[1], bb, acc[1][nt], 0, 0, 0);
    }
    ca[0] = na[0]; ca[1] = na[1];
  }
  __syncthreads();   // h1f/xs/xw dead; redS/redSS alias them (stores long done)

  #pragma unroll
  for (int mt = 0; mt < 2; ++mt)
    #pragma unroll
    for (int r = 0; r < 4; ++r) {
      int o = (wv * 2 + mt) * 16 + quad * 4 + r;
      float bo = b2c[o];
      float s = 0.f, ss = 0.f;
      #pragma unroll
      for (int nt = 0; nt < 8; ++nt) {
        float v = acc[mt][nt][r] + bo;
        s += v; ss += v * v;
      }
      redS[o * 17 + mn] = s;
      redSS[o * 17 + mn] = ss;
    }
  __syncthreads();
  {
    int o = threadIdx.x & 127;
    const float* src = (threadIdx.x < 128) ? redS : redSS;
    float s = 0.f;
    #pragma unroll
    for (int j = 0; j < 16; ++j) s += src[o * 17 + j];
    partials[blockIdx.x * 256 + threadIdx.x] = s;
  }
}

// ---------------------------------------------------------------------------
// Kernel 5: fp32 recompute of c2 head + bn2 + conv3(t=0) + tanh -> HRTF gather.
// One block per batch (grid 8).
// ---------------------------------------------------------------------------
__global__ __launch_bounds__(256) void finalize_spatial(
    const float* __restrict__ x,
    const float* __restrict__ W1c, const float* __restrict__ b1c,
    const float* __restrict__ coef1,
    const float* __restrict__ W2c, const float* __restrict__ b2c,
    const float* __restrict__ coef2,
    const float* __restrict__ W3c, const float* __restrict__ b3c,
    const float* __restrict__ hrtf, float* __restrict__ wgbuf)
{
  const int bb = blockIdx.x;
  __shared__ float xl[2 * 16];
  __shared__ float h1l[64 * 10];
  __shared__ float h2l[NH2 * 4];
  __shared__ float sp[6];
  const int tid = threadIdx.x;
  if (tid < 32) {
    int i = tid >> 4, j = tid & 15;
    int t = j - 6;
    xl[tid] = (t >= 0) ? x[(bb * 2 + i) * TLEN + t] : 0.f;
  }
  __syncthreads();
  if (tid < 64) {
    int ch = tid;
    float a1 = coef1[ch], d1 = coef1[64 + ch], bo = b1c[ch];
    for (int tt = 0; tt < 10; ++tt) {
      float acc = bo;
      #pragma unroll
      for (int i2 = 0; i2 < 2; ++i2)
        #pragma unroll
        for (int k = 0; k < 7; ++k)
          acc += xl[i2 * 16 + tt + k] * W1c[ch * 14 + i2 * 7 + k];
      float v = lrelu(a1 * acc + d1);
      h1l[ch * 10 + tt] = (tt >= 3) ? v : 0.f;
    }
  }
  __syncthreads();
  if (tid < NH2) {
    int o = tid;
    float a2 = coef2[o], d2 = coef2[NH2 + o], bo = b2c[o];
    float acc[4] = {bo, bo, bo, bo};
    for (int i = 0; i < 64; ++i)
      #pragma unroll
      for (int k = 0; k < 7; ++k) {
        float w = W2c[(o * 64 + i) * 7 + k];
        #pragma unroll
        for (int t = 0; t < 4; ++t)
          acc[t] += h1l[i * 10 + t + k] * w;
      }
    #pragma unroll
    for (int t = 0; t < 4; ++t)
      h2l[o * 4 + t] = lrelu(a2 * acc[t] + d2);
  }
  __syncthreads();
  if (tid < 6) {
    int c3 = tid;
    float acc = b3c[c3];
    for (int c = 0; c < NH2; ++c)
      #pragma unroll
      for (int k = 3; k < 7; ++k)
        acc += h2l[c * 4 + (k - 3)] * W3c[(c3 * NH2 + c) * 7 + k];
    sp[c3] = tanhf(acc);
  }
  __syncthreads();
  if (tid < 2) {
    int i = tid;
    float az = (sp[i * 3 + 0] + 1.f) * 0.5f * 11.f;
    float el = (sp[i * 3 + 1] + 1.f) * 0.5f * 4.f;
    float dist = (sp[i * 3 + 2] + 1.f) * 0.5f * 0.9f + 0.1f;
    int azi = min(max((int)az, 0), 11);
    int eli = min(max((int)el, 0), 4);
    int idx = eli * 12 + azi;
    for (int e = 0; e < 14; ++e)
      wgbuf[(bb * 2 + i) * 14 + e] = hrtf[idx * 14 + e] * dist;
  }
}

// ---------------------------------------------------------------------------
// Kernel 6 (v16): fused mix + renderer autocorrelation, XCH=1024, LDS-staged
// x (float4 interior path, scalar checked path for the boundary blocks).
// Grid XGRID (b = blk>>7, 1024-t chunks).
// ---------------------------------------------------------------------------
__global__ __launch_bounds__(256) void mix_xcorr(
    const float* __restrict__ x, const float* __restrict__ wgbuf,
    float* __restrict__ summed, float* __restrict__ partials)
{
  const int b = blockIdx.x >> 7;
  const int t0 = (blockIdx.x & (NCH - 1)) * XCH;
  const int tid = threadIdx.x;
  __shared__ float xs2[2][XCH + 20];   // col j <-> t = t0 - 8 + j
  __shared__ float zs[2][XCH + 8];
  __shared__ float redx[4][30];

  float wv[2][2][7];
  #pragma unroll
  for (int i = 0; i < 2; ++i)
    #pragma unroll
    for (int c = 0; c < 2; ++c)
      #pragma unroll
      for (int k = 0; k < 7; ++k)
        wv[i][c][k] = wgbuf[(b * 2 + i) * 14 + c * 7 + k];

  // ---- stage x: need t in [t0-8, t0+XCH+10) (mix cols up to u+k+5 max) ----
  const bool interior = (t0 >= 8) && (t0 + XCH + 12 <= TLEN);
  if (interior) {
    #pragma unroll
    for (int i = 0; i < 2; ++i) {
      const float* xp = &x[(size_t)(b * 2 + i) * TLEN + t0 - 8];
      *(float4*)&xs2[i][tid * 4] = *(const float4*)&xp[tid * 4];
      if (tid < 5)
        *(float4*)&xs2[i][XCH + tid * 4] = *(const float4*)&xp[XCH + tid * 4];
    }
  } else {
    for (int e = tid; e < 2 * (XCH + 20); e += 256) {
      int i = e / (XCH + 20), j = e % (XCH + 20);
      int tg = t0 - 8 + j;
      xs2[i][j] = (tg >= 0 && tg < TLEN) ? x[(size_t)(b * 2 + i) * TLEN + tg]
                                         : 0.f;
    }
  }
  __syncthreads();

  // ---- mix: 4 outputs/thread from LDS, write summed + zs ----
  const int tb = tid * 4;
  {
    float xl[2][10];
    #pragma unroll
    for (int i = 0; i < 2; ++i)
      #pragma unroll
      for (int j = 0; j < 10; ++j) xl[i][j] = xs2[i][tb + 5 + j];
    float acc[2][4] = {{0.f, 0.f, 0.f, 0.f}, {0.f, 0.f, 0.f, 0.f}};
    #pragma unroll
    for (int i = 0; i < 2; ++i)
      #pragma unroll
      for (int c = 0; c < 2; ++c)
        #pragma unroll
        for (int k = 0; k < 7; ++k)
          #pragma unroll
          for (int tt = 0; tt < 4; ++tt)
            acc[c][tt] += xl[i][tt + k] * wv[i][c][k];
    #pragma unroll
    for (int c = 0; c < 2; ++c) {
      *(float4*)&zs[c][tb] =
          make_float4(acc[c][0], acc[c][1], acc[c][2], acc[c][3]);
      *reinterpret_cast<float4*>(&summed[(size_t)(b * 2 + c) * TLEN + t0 + tb]) =
          make_float4(acc[c][0], acc[c][1], acc[c][2], acc[c][3]);
    }
  }
  // halo cols XCH..XCH+6 (owned by next chunk; recomputed, not written out).
  if (tid < 7) {
    int t = t0 + XCH + tid;
    float s0 = 0.f, s1 = 0.f;
    if (t < TLEN) {
      #pragma unroll
      for (int i = 0; i < 2; ++i)
        #pragma unroll
        for (int k = 0; k < 7; ++k) {
          float xv = xs2[i][XCH + tid + 5 + k];
          s0 += xv * wv[i][0][k];
          s1 += xv * wv[i][1][k];
        }
    }
    zs[0][XCH + tid] = s0;
    zs[1][XCH + tid] = s1;
  }
  if (tid == 7) { zs[0][XCH + 7] = 0.f; zs[1][XCH + 7] = 0.f; }
  __syncthreads();

  // ---- xcorr partials over this chunk ----
  float acc[30];
  #pragma unroll
  for (int q = 0; q < 30; ++q) acc[q] = 0.f;
  #pragma unroll
  for (int tt = 0; tt < 4; ++tt) {
    int j = tb + tt;
    float z0 = zs[0][j], z1 = zs[1][j];
    acc[28] += z0; acc[29] += z1;
    #pragma unroll
    for (int d = 0; d < 7; ++d) {
      float a0 = zs[0][j + d], a1 = zs[1][j + d];
      acc[d]      += z0 * a0;
      acc[7 + d]  += z0 * a1;
      acc[14 + d] += z1 * a0;
      acc[21 + d] += z1 * a1;
    }
  }
  #pragma unroll
  for (int q = 0; q < 30; ++q)
    #pragma unroll
    for (int m = 1; m <= 32; m <<= 1)
      acc[q] += __shfl_xor(acc[q], m, 64);
  const int lane = tid & 63, wvx = tid >> 6;
  if (lane == 0)
    #pragma unroll
    for (int q = 0; q < 30; ++q) redx[wvx][q] = acc[q];
  __syncthreads();
  if (tid < 30)
    partials[blockIdx.x * 30 + tid] =
        redx[0][tid] + redx[1][tid] + redx[2][tid] + redx[3][tid];
}

// ---------------------------------------------------------------------------
// Shared tail for the final kernels: bn2 coef hoist + h2t epilogue + conv3 +
// gather.
// ---------------------------------------------------------------------------
__device__ __forceinline__ void final_tail(
    int b, int t0, f32x4 (&acc)[2][8],
    const float* __restrict__ coef2,
    const unsigned short* __restrict__ w3g, const float* __restrict__ rb3c,
    unsigned short* h2t, unsigned short* dq, float* __restrict__ out)
{
  const int lane = threadIdx.x & 63;
  const int wv = threadIdx.x >> 6;
  const int mn = lane & 15, quad = lane >> 4;

  // hoist bn2 coefficients (b2 already folded into coef2[2*NH2+o])
  float a2v[2][4], dd2[2][4];
  #pragma unroll
  for (int mt = 0; mt < 2; ++mt)
    #pragma unroll
    for (int r = 0; r < 4; ++r) {
      int o = (wv * 2 + mt) * 16 + quad * 4 + r;
      a2v[mt][r] = coef2[o];
      dd2[mt][r] = coef2[2 * NH2 + o];
    }
  __syncthreads();   // h1f (and staging) dead; h2t aliases them

  // ---- bn2 + lrelu -> h2t fp16 [j'][ch]; j' <-> t = t0-3+j' ----
  #pragma unroll
  for (int nt = 0; nt < 8; ++nt) {
    int jp = nt * 16 + mn;
    int t = t0 - 3 + jp;
    bool ok = (t >= 0) && (t < TLEN);
    #pragma unroll
    for (int mt = 0; mt < 2; ++mt) {
      int obase = (wv * 2 + mt) * 16 + quad * 4;
      unsigned us[4];
      #pragma unroll
      for (int r = 0; r < 4; ++r) {
        float v = lrelu(a2v[mt][r] * acc[mt][nt][r] + dd2[mt][r]);
        us[r] = h16(ok ? v : 0.f);
      }
      *(uint2*)(h2t + jp * 136 + obase) =
          make_uint2(us[0] | (us[1] << 16), us[2] | (us[3] << 16));
    }
  }
  __syncthreads();

  // ---- conv3: D'[m=oc*7+tap][n=j'] = sum_ch W3 * h2 ----
  const int nt0 = wv * 2;
  f32x4 acc3[2];
  #pragma unroll
  for (int i = 0; i < 2; ++i) {
    f32x4 z = {0.f, 0.f, 0.f, 0.f};
    acc3[i] = z;
  }
  #pragma unroll
  for (int c = 0; c < 4; ++c) {
    f16x8 A3 = *(const f16x8*)(w3g + c * 512 + mn * 32 + quad * 8);
    #pragma unroll
    for (int i = 0; i < 2; ++i) {
      f16x8 bb = *(const f16x8*)(h2t + ((nt0 + i) * 16 + mn) * 136 + c * 32 + quad * 8);
      acc3[i] = __builtin_amdgcn_mfma_f32_16x16x32_f16(A3, bb, acc3[i], 0, 0, 0);
    }
  }
  #pragma unroll
  for (int i = 0; i < 2; ++i) {
    int n = (nt0 + i) * 16 + mn;
    unsigned us[4];
    #pragma unroll
    for (int r = 0; r < 4; ++r) us[r] = h16(acc3[i][r]);
    *(uint2*)(dq + n * 20 + quad * 4) =
        make_uint2(us[0] | (us[1] << 16), us[2] | (us[3] << 16));
  }
  __syncthreads();

  // ---- gather: out[oc][u] = ftanh(b3 + sum_tap D'[u+tap][oc*7+tap]) ----
  {
    int tid = threadIdx.x;
    if (tid < 240) {
      int oc = (tid >= FT) ? 1 : 0;
      int u = tid - oc * FT;
      float s = rb3c[oc];
      #pragma unroll
      for (int tap = 0; tap < 7; ++tap)
        s += fh16(dq[(u + tap) * 20 + oc * 7 + tap]);
      int t = t0 + u;
      if (t < TLEN) out[(b * 2 + oc) * TLEN + t] = ftanh(s);
    }
  }
}

// conv2 main loop from an LDS h1f tile (shared by both final variants).
__device__ __forceinline__ void conv2_loop(
    const unsigned short* h1f, const unsigned short* __restrict__ w2f,
    f32x4 (&acc)[2][8])
{
  const int lane = threadIdx.x & 63;
  const int wv = threadIdx.x >> 6;
  const int mn = lane & 15, quad = lane >> 4;
  #pragma unroll
  for (int mt = 0; mt < 2; ++mt)
    #pragma unroll
    for (int nt = 0; nt < 8; ++nt) {
      f32x4 z = {0.f, 0.f, 0.f, 0.f};
      acc[mt][nt] = z;
    }
  f16x8 ca[2], na[2];
  auto loadA = [&](int c, f16x8 (&A)[2]) {
    #pragma unroll
    for (int mt = 0; mt < 2; ++mt)
      A[mt] = *(const f16x8*)(w2f + (c * 8 + wv * 2 + mt) * 512 + mn * 32 + quad * 8);
  };
  loadA(0, ca);
  #pragma unroll
  for (int c = 0; c < 14; ++c) {
    if (c < 13) loadA(c + 1, na);
    const int tap = c >> 1;
    const int ch0 = (c & 1) * 32 + quad * 8;
    #pragma unroll
    for (int nt = 0; nt < 8; ++nt) {
      f16x8 bb = *(const f16x8*)(h1f + (nt * 16 + mn + tap) * 72 + ch0);
      acc[0][nt] = __builtin_amdgcn_mfma_f32_16x16x32_f16(ca[0], bb, acc[0][nt], 0, 0, 0);
      acc[1][nt] = __builtin_amdgcn_mfma_f32_16x16x32_f16(ca[1], bb, acc[1][nt], 0, 0, 0);
    }
    ca[0] = na[0]; ca[1] = na[1];
  }
}

// ---------------------------------------------------------------------------
// Kernel 11 (fallback): recompute h1 locally, then conv2 + tail.
// LDS 39,936 B.
// ---------------------------------------------------------------------------
__global__ __launch_bounds__(256, 4) void conv2_final_mfma(
    const float* __restrict__ xin,
    const unsigned short* __restrict__ w1f, const float* __restrict__ b1c,
    const float* __restrict__ coef1,
    const unsigned short* __restrict__ w2f,
    const float* __restrict__ coef2,
    const unsigned short* __restrict__ w3g, const float* __restrict__ rb3c,
    float* __restrict__ out)
{
  const int b  = blockIdx.y;
  const int t0 = blockIdx.x * FT;

  __shared__ __align__(16) char smem[39936];
  unsigned short* h1f = (unsigned short*)smem;          // [144][72], r <-> t0-6+r
  float* xs = (float*)(smem + 20736);                   // [2][168], j <-> t0-9+j
  unsigned short* xw = (unsigned short*)(smem + 22080); // [144][32]
  unsigned short* h2t = (unsigned short*)smem;          // [128][136] (late alias)
  unsigned short* dq  = (unsigned short*)(smem + 34816);// [128][20]

  stage_x(t0, 9, xin, b, xs);
  __syncthreads();
  h1_mfma<6>(t0, xs, xw, w1f, coef1, b1c, h1f);
  __syncthreads();

  f32x4 acc[2][8];
  conv2_loop(h1f, w2f, acc);
  final_tail(b, t0, acc, coef2, w3g, rb3c, h2t, dq, out);
}

// ---------------------------------------------------------------------------
// Kernel 11b (mid-ws path): load saved h1 from global (bit-identical to the
// local recompute), then conv2 + tail. LDS 39,936 B.
// ---------------------------------------------------------------------------
__global__ __launch_bounds__(256, 4) void conv2_final_h1(
    const unsigned short* __restrict__ h1g,
    const unsigned short* __restrict__ w2f,
    const float* __restrict__ coef2,
    const unsigned short* __restrict__ w3g, const float* __restrict__ rb3c,
    float* __restrict__ out)
{
  const int b  = blockIdx.y;
  const int t0 = blockIdx.x * FT;

  __shared__ __align__(16) char smem[39936];
  unsigned short* h1f = (unsigned short*)smem;          // [144][72], r <-> t0-6+r
  unsigned short* h2t = (unsigned short*)smem;          // [128][136] (late alias)
  unsigned short* dq  = (unsigned short*)(smem + 34816);// [128][20]

  // load h1 rows r 0..143 <-> t = t0-6+r; 8 threads x 16B per row, coalesced.
  for (int e = threadIdx.x; e < 144 * 8; e += 256) {
    int r = e >> 3, c8 = (e & 7) * 8;
    int t = t0 - 6 + r;
    uint4 v = make_uint4(0, 0, 0, 0);
    if (t >= 0 && t < TLEN)
      v = *(const uint4*)(h1g + ((size_t)(b * TLEN + t) * 64 + c8));
    *(uint4*)(h1f + r * 72 + c8) = v;
  }
  __syncthreads();

  f32x4 acc[2][8];
  conv2_loop(h1f, w2f, acc);
  final_tail(b, t0, acc, coef2, w3g, rb3c, h2t, dq, out);
}

// ---------------------------------------------------------------------------
extern "C" void kernel_launch(void* const* d_in, const int* in_sizes, int n_in,
                              void* d_out, int out_size, void* d_ws, size_t ws_size,
                              hipStream_t stream)
{
  (void)in_sizes; (void)n_in; (void)out_size;
  const float* x    = (const float*)d_in[0];
  const float* W1   = (const float*)d_in[1];
  const float* b1   = (const float*)d_in[2];
  const float* g1   = (const float*)d_in[3];
  const float* be1  = (const float*)d_in[4];
  const float* W2   = (const float*)d_in[5];
  const float* b2   = (const float*)d_in[6];
  const float* g2   = (const float*)d_in[7];
  const float* be2  = (const float*)d_in[8];
  const float* W3   = (const float*)d_in[9];
  const float* b3   = (const float*)d_in[10];
  const float* hrtf = (const float*)d_in[11];
  const float* RW1  = (const float*)d_in[12];
  const float* rb1  = (const float*)d_in[13];
  const float* rg1  = (const float*)d_in[14];
  const float* rbe1 = (const float*)d_in[15];
  const float* RW2  = (const float*)d_in[16];
  const float* rb2  = (const float*)d_in[17];
  const float* rg2  = (const float*)d_in[18];
  const float* rbe2 = (const float*)d_in[19];
  const float* RW3  = (const float*)d_in[20];
  const float* rb3  = (const float*)d_in[21];
  float* out = (float*)d_out;

  // d_out doubles as the 8192x256-f stats-partials buffer (lifetime ends
  // before the final kernel writes output).
  float* partialsB = (float*)d_out;

  char* ws = (char*)d_ws;
  float* partialsA      = (float*)(ws + 0);        // 524,288 B (xcorr partials)
  float* summed         = (float*)(ws + 524288);   // 8,388,608 B
  float* coef1          = (float*)(ws + 8912896);  // 128 f
  float* coef2          = (float*)(ws + 8913408);  // 384 f (a, d, d+a*b2)
  float* coefR1         = (float*)(ws + 8914944);  // 128 f
  float* coefR2         = (float*)(ws + 8915456);  // 384 f
  float* wgbuf          = (float*)(ws + 8916992);  // 224 f
  unsigned short* w2sp  = (unsigned short*)(ws + 8918016);  // 114,688 B
  unsigned short* w2re  = (unsigned short*)(ws + 9032704);  // 114,688 B
  unsigned short* w3g   = (unsigned short*)(ws + 9147392);  // 4,096 B
  unsigned short* w1sp  = (unsigned short*)(ws + 9151488);  // 4,096 B
  unsigned short* w1re  = (unsigned short*)(ws + 9155584);  // 4,096 B
  // mid-ws extension: renderer h1 (post-bn1/lrelu fp16), [b*TLEN+t][64ch]
  unsigned short* h1g   = (unsigned short*)(ws + 16777216); // 134,217,728 B
  const size_t WS_NEEDED_MID = 16777216ull + 134217728ull;  // 150,994,944
  const bool mid = ws_size >= WS_NEEDED_MID;

  prep_weights<<<472, 256, 0, stream>>>(W2, RW2, RW3, W1, RW1,
                                        w2sp, w2re, w3g, w1sp, w1re);
  // ---- spatial parameter network ----
  xcorr_stats<<<XGRID, 256, 0, stream>>>(x, partialsA);
  assemble_coef1<<<1, 256, 0, stream>>>(partialsA, XGRID, W1, b1, g1, be1, coef1);
  conv2_stats_mfma<0><<<8192, 256, 0, stream>>>(x, w1sp, b1, coef1, w2sp,
                                                b2, partialsB, nullptr);
  reduce_coef<<<128, 256, 0, stream>>>(partialsB, 8192, 128, b2, g2, be2, coef2);
  finalize_spatial<<<8, 256, 0, stream>>>(x, W1, b1, coef1, W2, b2, coef2,
                                          W3, b3, hrtf, wgbuf);
  // ---- HRTF mixing fused with renderer autocorrelation ----
  mix_xcorr<<<XGRID, 256, 0, stream>>>(x, wgbuf, summed, partialsA);
  // ---- binaural renderer ----
  assemble_coef1<<<1, 256, 0, stream>>>(partialsA, XGRID, RW1, rb1, rg1, rbe1, coefR1);
  if (mid) {
    conv2_stats_mfma<1><<<8192, 256, 0, stream>>>(summed, w1re, rb1, coefR1,
                                                  w2re, rb2, partialsB, h1g);
  } else {
    conv2_stats_mfma<0><<<8192, 256, 0, stream>>>(summed, w1re, rb1, coefR1,
                                                  w2re, rb2, partialsB, nullptr);
  }
  reduce_coef<<<128, 256, 0, stream>>>(partialsB, 8192, 128, rb2, rg2, rbe2, coefR2);
  if (mid) {
    conv2_final_h1<<<dim3(FGRID, NB), 256, 0, stream>>>(
        h1g, w2re, coefR2, w3g, rb3, out);
  } else {
    conv2_final_mfma<<<dim3(FGRID, NB), 256, 0, stream>>>(
        summed, w1re, rb1, coefR1, w2re, coefR2, w3g, rb3, out);
  }
}

// Round 7
// 562.504 us; speedup vs baseline: 1.0968x; 1.0968x over previous
//
#include <hip/hip_runtime.h>
#include <hip/hip_fp16.h>
#include <cstddef>

// ---------------------------------------------------------------------------
// SpatialAudioRenderer on MI355X — v17: kill the serial reduction phases.
//
// v16: 617us (~596 clock-adj; counters show ~3.5% clock drop vs v15's 603).
// Remaining non-conv2 budget ~220us: 1-block assemble_coef1 x2 (GPU-idle
// latency chains), 180 shuffle-ops/thread reduce tails, launch gaps. v17:
//  - reduce30 kernel (grid 30): partials[1024][30] -> R[30] in parallel;
//    assemble_coef1 reads R directly (serial chunk loop deleted). x2 paths.
//  - xcorr/mix butterfly 6->4 steps + 16-row LDS tree (-60 shfl/thread).
//  - prep_weights folded into the spatial xcorr launch (one fewer dispatch).
// conv2-family kernels byte-identical to v15/v16.
// ---------------------------------------------------------------------------

#define TLEN 131072
#define NB 8
#define NICH 2
#define NHID 64
#define NH2 128
#define EPSV 1e-5f
#define CNTF 1048576.0f  // NB * TLEN
#define FT 120           // final-kernel output tile
#define FGRID 1093       // ceil(TLEN / FT)
#define XCH 1024         // xcorr t-chunk
#define NCH 128          // TLEN / XCH
#define XGRID 1024       // NB * NCH
#define PREPB 472        // prep_weights block count

typedef _Float16 f16x8 __attribute__((ext_vector_type(8)));
typedef float f32x4 __attribute__((ext_vector_type(4)));

__device__ __forceinline__ float lrelu(float v) { return fmaxf(v, 0.2f * v); }
__device__ __forceinline__ unsigned short h16(float v) {
  return __half_as_ushort(__float2half(v));
}
__device__ __forceinline__ float fh16(unsigned short u) {
  return __half2float(__ushort_as_half(u));
}
// fast tanh for the OUTPUT path only (error ~1e-6; correct +/-1 limits).
__device__ __forceinline__ float ftanh(float x) {
  float e = __expf(2.f * x);
  return 1.f - 2.f / (e + 1.f);
}

// ---------------------------------------------------------------------------
// prep body (device): weight repacks.
//  w2sp/w2re: fragment-contiguous conv2 A (v8 layout).
//  w3g:       conv3 A' [c*512 + m*32 + ch%32].
//  w1sp/w1re: conv1 A, frag m: [m*512 + mn*32 + (i*16+kk)], kk<7 valid.
// ---------------------------------------------------------------------------
__device__ __forceinline__ void prep_body(
    int e,
    const float* __restrict__ W2c, const float* __restrict__ RW2c,
    const float* __restrict__ RW3c,
    const float* __restrict__ W1c, const float* __restrict__ RW1c,
    unsigned short* __restrict__ w2sp, unsigned short* __restrict__ w2re,
    unsigned short* __restrict__ w3g,
    unsigned short* __restrict__ w1sp, unsigned short* __restrict__ w1re)
{
  if (e < 114688) {
    int e2 = (e >= 57344) ? e - 57344 : e;
    int frag = e2 >> 9, within = e2 & 511;
    int c = frag >> 3, mt = frag & 7;
    int mn = within >> 5, kk = within & 31;
    int o = mt * 16 + mn;
    int tap = c >> 1, ch = (c & 1) * 32 + kk;
    const float* src = (e >= 57344) ? RW2c : W2c;
    unsigned short* dst = (e >= 57344) ? w2re : w2sp;
    dst[e2] = h16(src[(o * 64 + ch) * 7 + tap]);
  } else if (e < 116736) {
    int e2 = e - 114688;
    int c = e2 >> 9, within = e2 & 511;
    int m = within >> 5, kk = within & 31;
    int ch = c * 32 + kk;
    w3g[e2] = (m < 14) ? h16(RW3c[((m / 7) * 128 + ch) * 7 + (m % 7)])
                       : (unsigned short)0;
  } else if (e < 120832) {
    int e2 = e - 116736;
    int which = (e2 >= 2048);
    int e3 = e2 & 2047;
    int m = e3 >> 9, w = e3 & 511;
    int mn = w >> 5, K = w & 31;
    int i = K >> 4, kk = K & 15;
    const float* src = which ? RW1c : W1c;
    unsigned short* dst = which ? w1re : w1sp;
    dst[e3] = (kk < 7) ? h16(src[(m * 16 + mn) * 14 + i * 7 + kk])
                       : (unsigned short)0;
  }
}

// ---------------------------------------------------------------------------
// shared reduce tail for xcorr kernels: 4-step butterfly (16-lane groups) +
// 16-row LDS tree -> partials[block][30].
// ---------------------------------------------------------------------------
__device__ __forceinline__ void xcorr_reduce_tail(
    float (&acc)[30], float (*redx)[30], float* __restrict__ partials)
{
  #pragma unroll
  for (int q = 0; q < 30; ++q)
    #pragma unroll
    for (int m = 1; m <= 8; m <<= 1)
      acc[q] += __shfl_xor(acc[q], m, 64);
  const int lane = threadIdx.x & 63, wv = threadIdx.x >> 6;
  if ((lane & 15) == 0) {
    int row = wv * 4 + (lane >> 4);
    #pragma unroll
    for (int q = 0; q < 30; ++q) redx[row][q] = acc[q];
  }
  __syncthreads();
  if (threadIdx.x < 30) {
    float s = 0.f;
    #pragma unroll
    for (int r = 0; r < 16; ++r) s += redx[r][threadIdx.x];
    partials[blockIdx.x * 30 + threadIdx.x] = s;
  }
}

// ---------------------------------------------------------------------------
// Kernel A (v17): fused spatial xcorr + weight prep.
// blocks [0, XGRID): autocorrelation partials (30/block) over x.
// blocks [XGRID, XGRID+PREPB): weight repack.
// ---------------------------------------------------------------------------
__global__ __launch_bounds__(256) void xcorr_prep(
    const float* __restrict__ z, float* __restrict__ partials,
    const float* __restrict__ W2c, const float* __restrict__ RW2c,
    const float* __restrict__ RW3c,
    const float* __restrict__ W1c, const float* __restrict__ RW1c,
    unsigned short* __restrict__ w2sp, unsigned short* __restrict__ w2re,
    unsigned short* __restrict__ w3g,
    unsigned short* __restrict__ w1sp, unsigned short* __restrict__ w1re)
{
  if (blockIdx.x >= XGRID) {
    int e = (blockIdx.x - XGRID) * 256 + threadIdx.x;
    prep_body(e, W2c, RW2c, RW3c, W1c, RW1c, w2sp, w2re, w3g, w1sp, w1re);
    return;
  }
  const int b = blockIdx.x >> 7;
  const int t0 = (blockIdx.x & (NCH - 1)) * XCH;
  __shared__ float zs[2][XCH + 8];
  __shared__ float redx[16][30];
  #pragma unroll
  for (int i = 0; i < 2; ++i) {
    const float* zp = &z[(size_t)(b * 2 + i) * TLEN + t0];
    *(float4*)&zs[i][threadIdx.x * 4] = *(const float4*)&zp[threadIdx.x * 4];
    if (threadIdx.x < 7) {
      int tg = t0 + XCH + threadIdx.x;
      zs[i][XCH + threadIdx.x] =
          (tg < TLEN) ? z[(size_t)(b * 2 + i) * TLEN + tg] : 0.f;
    }
    if (threadIdx.x == 7) zs[i][XCH + 7] = 0.f;
  }
  __syncthreads();

  float acc[30];
  #pragma unroll
  for (int q = 0; q < 30; ++q) acc[q] = 0.f;
  const int tb = threadIdx.x * 4;
  #pragma unroll
  for (int tt = 0; tt < 4; ++tt) {
    int j = tb + tt;
    float z0 = zs[0][j], z1 = zs[1][j];
    acc[28] += z0; acc[29] += z1;
    #pragma unroll
    for (int d = 0; d < 7; ++d) {
      float a0 = zs[0][j + d], a1 = zs[1][j + d];
      acc[d]      += z0 * a0;
      acc[7 + d]  += z0 * a1;
      acc[14 + d] += z1 * a0;
      acc[21 + d] += z1 * a1;
    }
  }
  xcorr_reduce_tail(acc, redx, partials);
}

// ---------------------------------------------------------------------------
// Kernel R: reduce30 — partials[nblocks][30] -> R[30], full-GPU parallel.
// ---------------------------------------------------------------------------
__global__ __launch_bounds__(256) void reduce30(
    const float* __restrict__ partials, int nblocks, float* __restrict__ R)
{
  const int q = blockIdx.x;
  float s = 0.f;
  for (int j = threadIdx.x; j < nblocks; j += 256)
    s += partials[j * 30 + q];
  #pragma unroll
  for (int m = 1; m <= 32; m <<= 1) s += __shfl_xor(s, m, 64);
  __shared__ float rs[4];
  if ((threadIdx.x & 63) == 0) rs[threadIdx.x >> 6] = s;
  __syncthreads();
  if (threadIdx.x == 0) R[q] = rs[0] + rs[1] + rs[2] + rs[3];
}

// ---------------------------------------------------------------------------
// Kernel B (v17): assemble coef1 from precomputed R[30] (reduce30 output).
// ---------------------------------------------------------------------------
__global__ __launch_bounds__(256) void assemble_coef1(
    const float* __restrict__ Rg,
    const float* __restrict__ W1c, const float* __restrict__ b1c,
    const float* __restrict__ g, const float* __restrict__ be,
    float* __restrict__ coef)
{
  __shared__ float R[30];
  __shared__ float w1s[64 * 14];
  for (int e = threadIdx.x; e < 64 * 14; e += 256) w1s[e] = W1c[e];
  if (threadIdx.x < 30) R[threadIdx.x] = Rg[threadIdx.x];
  __syncthreads();
  if (threadIdx.x < 64) {
    int o = threadIdx.x;
    const float* w = &w1s[o * 14];
    float b1v = b1c[o];
    float sy = 0.f;
    #pragma unroll
    for (int i = 0; i < 2; ++i)
      #pragma unroll
      for (int k = 0; k < 7; ++k) sy += w[i * 7 + k] * R[28 + i];
    float syy = 0.f;
    #pragma unroll
    for (int i = 0; i < 2; ++i)
      #pragma unroll
      for (int k = 0; k < 7; ++k) {
        float wv = w[i * 7 + k];
        #pragma unroll
        for (int i2 = 0; i2 < 2; ++i2)
          #pragma unroll
          for (int k2 = 0; k2 < 7; ++k2) {
            int d = k2 - k;
            float r = (d >= 0) ? R[i * 14 + i2 * 7 + d]
                               : R[i2 * 14 + i * 7 - d];
            syy += wv * w[i2 * 7 + k2] * r;
          }
      }
    float S1 = CNTF * b1v + sy;
    float S2 = 2.f * b1v * S1 - CNTF * b1v * b1v + syy;
    float mean = S1 / CNTF;
    float var = S2 / CNTF - mean * mean;
    float a = g[o] * rsqrtf(var + EPSV);
    coef[o] = a;
    coef[64 + o] = be[o] - mean * a;
  }
}

// ---------------------------------------------------------------------------
// Kernel 2: reduce conv2-stats partials -> bn affine coefs.
// Emits coef[2C+c] = d + a*b (b2 folded for the final epilogue).
// ---------------------------------------------------------------------------
__global__ __launch_bounds__(256) void reduce_coef(
    const float* __restrict__ partials, int nblocks, int C,
    const float* __restrict__ bso,
    const float* __restrict__ g, const float* __restrict__ be,
    float* __restrict__ coef)
{
  const int c = blockIdx.x;
  float s = 0.f, ss = 0.f;
  for (int j = threadIdx.x; j < nblocks; j += 256) {
    s  += partials[j * 2 * C + c];
    ss += partials[j * 2 * C + C + c];
  }
  #pragma unroll
  for (int off = 32; off >= 1; off >>= 1) {
    s  += __shfl_down(s, off, 64);
    ss += __shfl_down(ss, off, 64);
  }
  __shared__ float rs[4], rss[4];
  const int lane = threadIdx.x & 63, wv = threadIdx.x >> 6;
  if (lane == 0) { rs[wv] = s; rss[wv] = ss; }
  __syncthreads();
  if (threadIdx.x == 0) {
    float st  = rs[0] + rs[1] + rs[2] + rs[3];
    float sst = rss[0] + rss[1] + rss[2] + rss[3];
    float mean = st / CNTF;
    float var  = sst / CNTF - mean * mean;
    float a = g[c] * rsqrtf(var + EPSV);
    float d = be[c] - mean * a;
    coef[c] = a;
    coef[C + c] = d;
    coef[2 * C + c] = d + a * bso[c];
  }
}

// ---------------------------------------------------------------------------
// Shared: stage x (fp32, 168 cols) then h1 via MFMA.
// xs col j <-> t = t0 - HOF - 3 + j.  h1f row r <-> t = t0 - HOF + r.
// B tile xw[n][K=i*16+kk] = xs[i][n+kk] (kk<7), built in LDS; A from w1f.
// ---------------------------------------------------------------------------
__device__ __forceinline__ void stage_x(
    int t0, int xoff, const float* __restrict__ xin, int b, float* xs)
{
  for (int e = threadIdx.x; e < 2 * 168; e += 256) {
    int i = e / 168, j = e % 168;
    int tg = t0 - xoff + j;
    xs[e] = (tg >= 0 && tg < TLEN) ? xin[(b * NICH + i) * TLEN + tg] : 0.f;
  }
}

template<int HOF>
__device__ __forceinline__ void h1_mfma(
    int t0, const float* xs, unsigned short* xw,
    const unsigned short* __restrict__ w1f,
    const float* __restrict__ coef1, const float* __restrict__ b1c,
    unsigned short* h1f)
{
  // build im2col B tile: 144 rows x 32 halfs
  for (int e = threadIdx.x; e < 144 * 2; e += 256) {
    int n = e >> 1, i = e & 1;
    const float* xp = &xs[i * 168 + n];
    unsigned short hv[7];
    #pragma unroll
    for (int kk = 0; kk < 7; ++kk) hv[kk] = h16(xp[kk]);
    *(uint4*)(xw + n * 32 + i * 16) = make_uint4(
        hv[0] | ((unsigned)hv[1] << 16), hv[2] | ((unsigned)hv[3] << 16),
        hv[4] | ((unsigned)hv[5] << 16), (unsigned)hv[6]);
    *(uint4*)(xw + n * 32 + i * 16 + 8) = make_uint4(0, 0, 0, 0);
  }
  __syncthreads();

  const int lane = threadIdx.x & 63;
  const int wv = threadIdx.x >> 6;
  const int mn = lane & 15, quad = lane >> 4;
  f16x8 A1 = *(const f16x8*)(w1f + wv * 512 + mn * 32 + quad * 8);
  f32x4 acc1[9];
  #pragma unroll
  for (int nt = 0; nt < 9; ++nt) {
    f32x4 z = {0.f, 0.f, 0.f, 0.f};
    acc1[nt] = z;
  }
  #pragma unroll
  for (int nt = 0; nt < 9; ++nt) {
    f16x8 bb = *(const f16x8*)(xw + (nt * 16 + mn) * 32 + quad * 8);
    acc1[nt] = __builtin_amdgcn_mfma_f32_16x16x32_f16(A1, bb, acc1[nt], 0, 0, 0);
  }
  // epilogue: bn1 (b1 folded) + lrelu + OOB zero -> h1f[n][ch]
  const int ch0 = wv * 16 + quad * 4;
  float a1v[4], dd[4];
  #pragma unroll
  for (int r = 0; r < 4; ++r) {
    a1v[r] = coef1[ch0 + r];
    dd[r]  = coef1[64 + ch0 + r] + a1v[r] * b1c[ch0 + r];
  }
  #pragma unroll
  for (int nt = 0; nt < 9; ++nt) {
    int n = nt * 16 + mn;
    int t = t0 - HOF + n;
    bool ok = (t >= 0) && (t < TLEN);
    unsigned us[4];
    #pragma unroll
    for (int r = 0; r < 4; ++r) {
      float v = lrelu(a1v[r] * acc1[nt][r] + dd[r]);
      us[r] = h16(ok ? v : 0.f);
    }
    *(uint2*)(h1f + n * 72 + ch0) =
        make_uint2(us[0] | (us[1] << 16), us[2] | (us[3] << 16));
  }
}

// ---------------------------------------------------------------------------
// Kernel 3/9: conv2 via fp16 MFMA, stats (+ optional h1 save).
// 128 o x 128 t per block; v10 mapping: 2M x 8N per wave, shared B across
// waves, prefetched A. LDS 31,296 B.
// SAVE==1: flush h1f rows 3..130 (post-bn1 fp16, bit-identical to the final
// kernel's recompute) to h1out, issued BEFORE the conv2 loop so stores retire
// under MFMA (v15).
// ---------------------------------------------------------------------------
template<int SAVE>
__global__ __launch_bounds__(256, 4) void conv2_stats_mfma(
    const float* __restrict__ xin,
    const unsigned short* __restrict__ w1f, const float* __restrict__ b1c,
    const float* __restrict__ coef1,
    const unsigned short* __restrict__ w2f,
    const float* __restrict__ b2c,
    float* __restrict__ partials,
    unsigned short* __restrict__ h1out)
{
  const int b  = blockIdx.x >> 10;
  const int t0 = (blockIdx.x & 1023) * 128;

  __shared__ __align__(16) char smem[31296];
  unsigned short* h1f = (unsigned short*)smem;          // [144][72], r <-> t0-3+r
  float* xs = (float*)(smem + 20736);                   // [2][168], j <-> t0-6+j
  unsigned short* xw = (unsigned short*)(smem + 22080); // [144][32]
  float* redS = (float*)smem;                           // [128][17] (late alias)
  float* redSS= (float*)(smem + 8704);

  stage_x(t0, 6, xin, b, xs);
  __syncthreads();
  h1_mfma<3>(t0, xs, xw, w1f, coef1, b1c, h1f);
  __syncthreads();

  if (SAVE == 1) {
    // h1f stable after the barrier above; stores ride out under the conv2
    // MFMA loop below. 128 rows x 64 ch fp16, coalesced uint4.
    for (int e = threadIdx.x; e < 1024; e += 256) {
      int row = e >> 3, c8 = (e & 7) * 8;
      *(uint4*)(h1out + ((size_t)(b * TLEN + t0 + row) * 64 + c8)) =
          *(const uint4*)(h1f + (row + 3) * 72 + c8);
    }
  }

  const int lane = threadIdx.x & 63;
  const int wv = threadIdx.x >> 6;
  const int mn = lane & 15, quad = lane >> 4;

  f32x4 acc[2][8];
  #pragma unroll
  for (int mt = 0; mt < 2; ++mt)
    #pragma unroll
    for (int nt = 0; nt < 8; ++nt) {
      f32x4 z = {0.f, 0.f, 0.f, 0.f};
      acc[mt][nt] = z;
    }

  f16x8 ca[2], na[2];
  auto loadA = [&](int c, f16x8 (&A)[2]) {
    #pragma unroll
    for (int mt = 0; mt < 2; ++mt)
      A[mt] = *(const f16x8*)(w2f + (c * 8 + wv * 2 + mt) * 512 + mn * 32 + quad * 8);
  };
  loadA(0, ca);
  #pragma unroll
  for (int c = 0; c < 14; ++c) {
    if (c < 13) loadA(c + 1, na);
    const int tap = c >> 1;
    const int ch0 = (c & 1) * 32 + quad * 8;
    #pragma unroll
    for (int nt = 0; nt < 8; ++nt) {
      f16x8 bb = *(const f16x8*)(h1f + (nt * 16 + mn + tap) * 72 + ch0);
      acc[0][nt] = __builtin_amdgcn_mfma_f32_16x16x32_f16(ca[0], bb, acc[0][nt], 0, 0, 0);
      acc[1][nt] = __builtin_amdgcn_mfma_f32_16x16x32_f16(ca[1], bb, acc[1][nt], 0, 0, 0);
    }
    ca[0] = na[0]; ca[1] = na[1];
  }
  __syncthreads();   // h1f/xs/xw dead; redS/redSS alias them (stores long done)

  #pragma unroll
  for (int mt = 0; mt < 2; ++mt)
    #pragma unroll
    for (int r = 0; r < 4; ++r) {
      int o = (wv * 2 + mt) * 16 + quad * 4 + r;
      float bo = b2c[o];
      float s = 0.f, ss = 0.f;
      #pragma unroll
      for (int nt = 0; nt < 8; ++nt) {
        float v = acc[mt][nt][r] + bo;
        s += v; ss += v * v;
      }
      redS[o * 17 + mn] = s;
      redSS[o * 17 + mn] = ss;
    }
  __syncthreads();
  {
    int o = threadIdx.x & 127;
    const float* src = (threadIdx.x < 128) ? redS : redSS;
    float s = 0.f;
    #pragma unroll
    for (int j = 0; j < 16; ++j) s += src[o * 17 + j];
    partials[blockIdx.x * 256 + threadIdx.x] = s;
  }
}

// ---------------------------------------------------------------------------
// Kernel 5: fp32 recompute of c2 head + bn2 + conv3(t=0) + tanh -> HRTF gather.
// One block per batch (grid 8).
// ---------------------------------------------------------------------------
__global__ __launch_bounds__(256) void finalize_spatial(
    const float* __restrict__ x,
    const float* __restrict__ W1c, const float* __restrict__ b1c,
    const float* __restrict__ coef1,
    const float* __restrict__ W2c, const float* __restrict__ b2c,
    const float* __restrict__ coef2,
    const float* __restrict__ W3c, const float* __restrict__ b3c,
    const float* __restrict__ hrtf, float* __restrict__ wgbuf)
{
  const int bb = blockIdx.x;
  __shared__ float xl[2 * 16];
  __shared__ float h1l[64 * 10];
  __shared__ float h2l[NH2 * 4];
  __shared__ float sp[6];
  const int tid = threadIdx.x;
  if (tid < 32) {
    int i = tid >> 4, j = tid & 15;
    int t = j - 6;
    xl[tid] = (t >= 0) ? x[(bb * 2 + i) * TLEN + t] : 0.f;
  }
  __syncthreads();
  if (tid < 64) {
    int ch = tid;
    float a1 = coef1[ch], d1 = coef1[64 + ch], bo = b1c[ch];
    for (int tt = 0; tt < 10; ++tt) {
      float acc = bo;
      #pragma unroll
      for (int i2 = 0; i2 < 2; ++i2)
        #pragma unroll
        for (int k = 0; k < 7; ++k)
          acc += xl[i2 * 16 + tt + k] * W1c[ch * 14 + i2 * 7 + k];
      float v = lrelu(a1 * acc + d1);
      h1l[ch * 10 + tt] = (tt >= 3) ? v : 0.f;
    }
  }
  __syncthreads();
  if (tid < NH2) {
    int o = tid;
    float a2 = coef2[o], d2 = coef2[NH2 + o], bo = b2c[o];
    float acc[4] = {bo, bo, bo, bo};
    for (int i = 0; i < 64; ++i)
      #pragma unroll
      for (int k = 0; k < 7; ++k) {
        float w = W2c[(o * 64 + i) * 7 + k];
        #pragma unroll
        for (int t = 0; t < 4; ++t)
          acc[t] += h1l[i * 10 + t + k] * w;
      }
    #pragma unroll
    for (int t = 0; t < 4; ++t)
      h2l[o * 4 + t] = lrelu(a2 * acc[t] + d2);
  }
  __syncthreads();
  if (tid < 6) {
    int c3 = tid;
    float acc = b3c[c3];
    for (int c = 0; c < NH2; ++c)
      #pragma unroll
      for (int k = 3; k < 7; ++k)
        acc += h2l[c * 4 + (k - 3)] * W3c[(c3 * NH2 + c) * 7 + k];
    sp[c3] = tanhf(acc);
  }
  __syncthreads();
  if (tid < 2) {
    int i = tid;
    float az = (sp[i * 3 + 0] + 1.f) * 0.5f * 11.f;
    float el = (sp[i * 3 + 1] + 1.f) * 0.5f * 4.f;
    float dist = (sp[i * 3 + 2] + 1.f) * 0.5f * 0.9f + 0.1f;
    int azi = min(max((int)az, 0), 11);
    int eli = min(max((int)el, 0), 4);
    int idx = eli * 12 + azi;
    for (int e = 0; e < 14; ++e)
      wgbuf[(bb * 2 + i) * 14 + e] = hrtf[idx * 14 + e] * dist;
  }
}

// ---------------------------------------------------------------------------
// Kernel 6: fused mix + renderer autocorrelation, XCH=1024, LDS-staged
// x (float4 interior path, scalar checked path for the boundary blocks).
// Grid XGRID (b = blk>>7, 1024-t chunks).
// ---------------------------------------------------------------------------
__global__ __launch_bounds__(256) void mix_xcorr(
    const float* __restrict__ x, const float* __restrict__ wgbuf,
    float* __restrict__ summed, float* __restrict__ partials)
{
  const int b = blockIdx.x >> 7;
  const int t0 = (blockIdx.x & (NCH - 1)) * XCH;
  const int tid = threadIdx.x;
  __shared__ float xs2[2][XCH + 20];   // col j <-> t = t0 - 8 + j
  __shared__ float zs[2][XCH + 8];
  __shared__ float redx[16][30];

  float wv[2][2][7];
  #pragma unroll
  for (int i = 0; i < 2; ++i)
    #pragma unroll
    for (int c = 0; c < 2; ++c)
      #pragma unroll
      for (int k = 0; k < 7; ++k)
        wv[i][c][k] = wgbuf[(b * 2 + i) * 14 + c * 7 + k];

  // ---- stage x: need t in [t0-8, t0+XCH+10) ----
  const bool interior = (t0 >= 8) && (t0 + XCH + 12 <= TLEN);
  if (interior) {
    #pragma unroll
    for (int i = 0; i < 2; ++i) {
      const float* xp = &x[(size_t)(b * 2 + i) * TLEN + t0 - 8];
      *(float4*)&xs2[i][tid * 4] = *(const float4*)&xp[tid * 4];
      if (tid < 5)
        *(float4*)&xs2[i][XCH + tid * 4] = *(const float4*)&xp[XCH + tid * 4];
    }
  } else {
    for (int e = tid; e < 2 * (XCH + 20); e += 256) {
      int i = e / (XCH + 20), j = e % (XCH + 20);
      int tg = t0 - 8 + j;
      xs2[i][j] = (tg >= 0 && tg < TLEN) ? x[(size_t)(b * 2 + i) * TLEN + tg]
                                         : 0.f;
    }
  }
  __syncthreads();

  // ---- mix: 4 outputs/thread from LDS, write summed + zs ----
  const int tb = tid * 4;
  {
    float xl[2][10];
    #pragma unroll
    for (int i = 0; i < 2; ++i)
      #pragma unroll
      for (int j = 0; j < 10; ++j) xl[i][j] = xs2[i][tb + 5 + j];
    float acc[2][4] = {{0.f, 0.f, 0.f, 0.f}, {0.f, 0.f, 0.f, 0.f}};
    #pragma unroll
    for (int i = 0; i < 2; ++i)
      #pragma unroll
      for (int c = 0; c < 2; ++c)
        #pragma unroll
        for (int k = 0; k < 7; ++k)
          #pragma unroll
          for (int tt = 0; tt < 4; ++tt)
            acc[c][tt] += xl[i][tt + k] * wv[i][c][k];
    #pragma unroll
    for (int c = 0; c < 2; ++c) {
      *(float4*)&zs[c][tb] =
          make_float4(acc[c][0], acc[c][1], acc[c][2], acc[c][3]);
      *reinterpret_cast<float4*>(&summed[(size_t)(b * 2 + c) * TLEN + t0 + tb]) =
          make_float4(acc[c][0], acc[c][1], acc[c][2], acc[c][3]);
    }
  }
  // halo cols XCH..XCH+6 (owned by next chunk; recomputed, not written out).
  if (tid < 7) {
    int t = t0 + XCH + tid;
    float s0 = 0.f, s1 = 0.f;
    if (t < TLEN) {
      #pragma unroll
      for (int i = 0; i < 2; ++i)
        #pragma unroll
        for (int k = 0; k < 7; ++k) {
          float xv = xs2[i][XCH + tid + 5 + k];
          s0 += xv * wv[i][0][k];
          s1 += xv * wv[i][1][k];
        }
    }
    zs[0][XCH + tid] = s0;
    zs[1][XCH + tid] = s1;
  }
  if (tid == 7) { zs[0][XCH + 7] = 0.f; zs[1][XCH + 7] = 0.f; }
  __syncthreads();

  // ---- xcorr partials over this chunk ----
  float acc[30];
  #pragma unroll
  for (int q = 0; q < 30; ++q) acc[q] = 0.f;
  #pragma unroll
  for (int tt = 0; tt < 4; ++tt) {
    int j = tb + tt;
    float z0 = zs[0][j], z1 = zs[1][j];
    acc[28] += z0; acc[29] += z1;
    #pragma unroll
    for (int d = 0; d < 7; ++d) {
      float a0 = zs[0][j + d], a1 = zs[1][j + d];
      acc[d]      += z0 * a0;
      acc[7 + d]  += z0 * a1;
      acc[14 + d] += z1 * a0;
      acc[21 + d] += z1 * a1;
    }
  }
  xcorr_reduce_tail(acc, redx, partials);
}

// ---------------------------------------------------------------------------
// Shared tail for the final kernels: bn2 coef hoist + h2t epilogue + conv3 +
// gather.
// ---------------------------------------------------------------------------
__device__ __forceinline__ void final_tail(
    int b, int t0, f32x4 (&acc)[2][8],
    const float* __restrict__ coef2,
    const unsigned short* __restrict__ w3g, const float* __restrict__ rb3c,
    unsigned short* h2t, unsigned short* dq, float* __restrict__ out)
{
  const int lane = threadIdx.x & 63;
  const int wv = threadIdx.x >> 6;
  const int mn = lane & 15, quad = lane >> 4;

  // hoist bn2 coefficients (b2 already folded into coef2[2*NH2+o])
  float a2v[2][4], dd2[2][4];
  #pragma unroll
  for (int mt = 0; mt < 2; ++mt)
    #pragma unroll
    for (int r = 0; r < 4; ++r) {
      int o = (wv * 2 + mt) * 16 + quad * 4 + r;
      a2v[mt][r] = coef2[o];
      dd2[mt][r] = coef2[2 * NH2 + o];
    }
  __syncthreads();   // h1f (and staging) dead; h2t aliases them

  // ---- bn2 + lrelu -> h2t fp16 [j'][ch]; j' <-> t = t0-3+j' ----
  #pragma unroll
  for (int nt = 0; nt < 8; ++nt) {
    int jp = nt * 16 + mn;
    int t = t0 - 3 + jp;
    bool ok = (t >= 0) && (t < TLEN);
    #pragma unroll
    for (int mt = 0; mt < 2; ++mt) {
      int obase = (wv * 2 + mt) * 16 + quad * 4;
      unsigned us[4];
      #pragma unroll
      for (int r = 0; r < 4; ++r) {
        float v = lrelu(a2v[mt][r] * acc[mt][nt][r] + dd2[mt][r]);
        us[r] = h16(ok ? v : 0.f);
      }
      *(uint2*)(h2t + jp * 136 + obase) =
          make_uint2(us[0] | (us[1] << 16), us[2] | (us[3] << 16));
    }
  }
  __syncthreads();

  // ---- conv3: D'[m=oc*7+tap][n=j'] = sum_ch W3 * h2 ----
  const int nt0 = wv * 2;
  f32x4 acc3[2];
  #pragma unroll
  for (int i = 0; i < 2; ++i) {
    f32x4 z = {0.f, 0.f, 0.f, 0.f};
    acc3[i] = z;
  }
  #pragma unroll
  for (int c = 0; c < 4; ++c) {
    f16x8 A3 = *(const f16x8*)(w3g + c * 512 + mn * 32 + quad * 8);
    #pragma unroll
    for (int i = 0; i < 2; ++i) {
      f16x8 bb = *(const f16x8*)(h2t + ((nt0 + i) * 16 + mn) * 136 + c * 32 + quad * 8);
      acc3[i] = __builtin_amdgcn_mfma_f32_16x16x32_f16(A3, bb, acc3[i], 0, 0, 0);
    }
  }
  #pragma unroll
  for (int i = 0; i < 2; ++i) {
    int n = (nt0 + i) * 16 + mn;
    unsigned us[4];
    #pragma unroll
    for (int r = 0; r < 4; ++r) us[r] = h16(acc3[i][r]);
    *(uint2*)(dq + n * 20 + quad * 4) =
        make_uint2(us[0] | (us[1] << 16), us[2] | (us[3] << 16));
  }
  __syncthreads();

  // ---- gather: out[oc][u] = ftanh(b3 + sum_tap D'[u+tap][oc*7+tap]) ----
  {
    int tid = threadIdx.x;
    if (tid < 240) {
      int oc = (tid >= FT) ? 1 : 0;
      int u = tid - oc * FT;
      float s = rb3c[oc];
      #pragma unroll
      for (int tap = 0; tap < 7; ++tap)
        s += fh16(dq[(u + tap) * 20 + oc * 7 + tap]);
      int t = t0 + u;
      if (t < TLEN) out[(b * 2 + oc) * TLEN + t] = ftanh(s);
    }
  }
}

// conv2 main loop from an LDS h1f tile (shared by both final variants).
__device__ __forceinline__ void conv2_loop(
    const unsigned short* h1f, const unsigned short* __restrict__ w2f,
    f32x4 (&acc)[2][8])
{
  const int lane = threadIdx.x & 63;
  const int wv = threadIdx.x >> 6;
  const int mn = lane & 15, quad = lane >> 4;
  #pragma unroll
  for (int mt = 0; mt < 2; ++mt)
    #pragma unroll
    for (int nt = 0; nt < 8; ++nt) {
      f32x4 z = {0.f, 0.f, 0.f, 0.f};
      acc[mt][nt] = z;
    }
  f16x8 ca[2], na[2];
  auto loadA = [&](int c, f16x8 (&A)[2]) {
    #pragma unroll
    for (int mt = 0; mt < 2; ++mt)
      A[mt] = *(const f16x8*)(w2f + (c * 8 + wv * 2 + mt) * 512 + mn * 32 + quad * 8);
  };
  loadA(0, ca);
  #pragma unroll
  for (int c = 0; c < 14; ++c) {
    if (c < 13) loadA(c + 1, na);
    const int tap = c >> 1;
    const int ch0 = (c & 1) * 32 + quad * 8;
    #pragma unroll
    for (int nt = 0; nt < 8; ++nt) {
      f16x8 bb = *(const f16x8*)(h1f + (nt * 16 + mn + tap) * 72 + ch0);
      acc[0][nt] = __builtin_amdgcn_mfma_f32_16x16x32_f16(ca[0], bb, acc[0][nt], 0, 0, 0);
      acc[1][nt] = __builtin_amdgcn_mfma_f32_16x16x32_f16(ca[1], bb, acc[1][nt], 0, 0, 0);
    }
    ca[0] = na[0]; ca[1] = na[1];
  }
}

// ---------------------------------------------------------------------------
// Kernel 11 (fallback): recompute h1 locally, then conv2 + tail.
// LDS 39,936 B.
// ---------------------------------------------------------------------------
__global__ __launch_bounds__(256, 4) void conv2_final_mfma(
    const float* __restrict__ xin,
    const unsigned short* __restrict__ w1f, const float* __restrict__ b1c,
    const float* __restrict__ coef1,
    const unsigned short* __restrict__ w2f,
    const float* __restrict__ coef2,
    const unsigned short* __restrict__ w3g, const float* __restrict__ rb3c,
    float* __restrict__ out)
{
  const int b  = blockIdx.y;
  const int t0 = blockIdx.x * FT;

  __shared__ __align__(16) char smem[39936];
  unsigned short* h1f = (unsigned short*)smem;          // [144][72], r <-> t0-6+r
  float* xs = (float*)(smem + 20736);                   // [2][168], j <-> t0-9+j
  unsigned short* xw = (unsigned short*)(smem + 22080); // [144][32]
  unsigned short* h2t = (unsigned short*)smem;          // [128][136] (late alias)
  unsigned short* dq  = (unsigned short*)(smem + 34816);// [128][20]

  stage_x(t0, 9, xin, b, xs);
  __syncthreads();
  h1_mfma<6>(t0, xs, xw, w1f, coef1, b1c, h1f);
  __syncthreads();

  f32x4 acc[2][8];
  conv2_loop(h1f, w2f, acc);
  final_tail(b, t0, acc, coef2, w3g, rb3c, h2t, dq, out);
}

// ---------------------------------------------------------------------------
// Kernel 11b (mid-ws path): load saved h1 from global (bit-identical to the
// local recompute), then conv2 + tail. LDS 39,936 B.
// ---------------------------------------------------------------------------
__global__ __launch_bounds__(256, 4) void conv2_final_h1(
    const unsigned short* __restrict__ h1g,
    const unsigned short* __restrict__ w2f,
    const float* __restrict__ coef2,
    const unsigned short* __restrict__ w3g, const float* __restrict__ rb3c,
    float* __restrict__ out)
{
  const int b  = blockIdx.y;
  const int t0 = blockIdx.x * FT;

  __shared__ __align__(16) char smem[39936];
  unsigned short* h1f = (unsigned short*)smem;          // [144][72], r <-> t0-6+r
  unsigned short* h2t = (unsigned short*)smem;          // [128][136] (late alias)
  unsigned short* dq  = (unsigned short*)(smem + 34816);// [128][20]

  // load h1 rows r 0..143 <-> t = t0-6+r; 8 threads x 16B per row, coalesced.
  for (int e = threadIdx.x; e < 144 * 8; e += 256) {
    int r = e >> 3, c8 = (e & 7) * 8;
    int t = t0 - 6 + r;
    uint4 v = make_uint4(0, 0, 0, 0);
    if (t >= 0 && t < TLEN)
      v = *(const uint4*)(h1g + ((size_t)(b * TLEN + t) * 64 + c8));
    *(uint4*)(h1f + r * 72 + c8) = v;
  }
  __syncthreads();

  f32x4 acc[2][8];
  conv2_loop(h1f, w2f, acc);
  final_tail(b, t0, acc, coef2, w3g, rb3c, h2t, dq, out);
}

// ---------------------------------------------------------------------------
extern "C" void kernel_launch(void* const* d_in, const int* in_sizes, int n_in,
                              void* d_out, int out_size, void* d_ws, size_t ws_size,
                              hipStream_t stream)
{
  (void)in_sizes; (void)n_in; (void)out_size;
  const float* x    = (const float*)d_in[0];
  const float* W1   = (const float*)d_in[1];
  const float* b1   = (const float*)d_in[2];
  const float* g1   = (const float*)d_in[3];
  const float* be1  = (const float*)d_in[4];
  const float* W2   = (const float*)d_in[5];
  const float* b2   = (const float*)d_in[6];
  const float* g2   = (const float*)d_in[7];
  const float* be2  = (const float*)d_in[8];
  const float* W3   = (const float*)d_in[9];
  const float* b3   = (const float*)d_in[10];
  const float* hrtf = (const float*)d_in[11];
  const float* RW1  = (const float*)d_in[12];
  const float* rb1  = (const float*)d_in[13];
  const float* rg1  = (const float*)d_in[14];
  const float* rbe1 = (const float*)d_in[15];
  const float* RW2  = (const float*)d_in[16];
  const float* rb2  = (const float*)d_in[17];
  const float* rg2  = (const float*)d_in[18];
  const float* rbe2 = (const float*)d_in[19];
  const float* RW3  = (const float*)d_in[20];
  const float* rb3  = (const float*)d_in[21];
  float* out = (float*)d_out;

  // d_out doubles as the 8192x256-f stats-partials buffer (lifetime ends
  // before the final kernel writes output).
  float* partialsB = (float*)d_out;

  char* ws = (char*)d_ws;
  float* partialsA      = (float*)(ws + 0);        // 524,288 B (xcorr partials)
  float* summed         = (float*)(ws + 524288);   // 8,388,608 B
  float* coef1          = (float*)(ws + 8912896);  // 128 f
  float* coef2          = (float*)(ws + 8913408);  // 384 f (a, d, d+a*b2)
  float* coefR1         = (float*)(ws + 8914944);  // 128 f
  float* coefR2         = (float*)(ws + 8915456);  // 384 f
  float* wgbuf          = (float*)(ws + 8916992);  // 224 f
  unsigned short* w2sp  = (unsigned short*)(ws + 8918016);  // 114,688 B
  unsigned short* w2re  = (unsigned short*)(ws + 9032704);  // 114,688 B
  unsigned short* w3g   = (unsigned short*)(ws + 9147392);  // 4,096 B
  unsigned short* w1sp  = (unsigned short*)(ws + 9151488);  // 4,096 B
  unsigned short* w1re  = (unsigned short*)(ws + 9155584);  // 4,096 B
  float* Rbuf           = (float*)(ws + 9159680);  // 30 f (reduce30 output)
  // mid-ws extension: renderer h1 (post-bn1/lrelu fp16), [b*TLEN+t][64ch]
  unsigned short* h1g   = (unsigned short*)(ws + 16777216); // 134,217,728 B
  const size_t WS_NEEDED_MID = 16777216ull + 134217728ull;  // 150,994,944
  const bool mid = ws_size >= WS_NEEDED_MID;

  // ---- spatial parameter network (xcorr fused with weight prep) ----
  xcorr_prep<<<XGRID + PREPB, 256, 0, stream>>>(
      x, partialsA, W2, RW2, RW3, W1, RW1, w2sp, w2re, w3g, w1sp, w1re);
  reduce30<<<30, 256, 0, stream>>>(partialsA, XGRID, Rbuf);
  assemble_coef1<<<1, 256, 0, stream>>>(Rbuf, W1, b1, g1, be1, coef1);
  conv2_stats_mfma<0><<<8192, 256, 0, stream>>>(x, w1sp, b1, coef1, w2sp,
                                                b2, partialsB, nullptr);
  reduce_coef<<<128, 256, 0, stream>>>(partialsB, 8192, 128, b2, g2, be2, coef2);
  finalize_spatial<<<8, 256, 0, stream>>>(x, W1, b1, coef1, W2, b2, coef2,
                                          W3, b3, hrtf, wgbuf);
  // ---- HRTF mixing fused with renderer autocorrelation ----
  mix_xcorr<<<XGRID, 256, 0, stream>>>(x, wgbuf, summed, partialsA);
  // ---- binaural renderer ----
  reduce30<<<30, 256, 0, stream>>>(partialsA, XGRID, Rbuf);
  assemble_coef1<<<1, 256, 0, stream>>>(Rbuf, RW1, rb1, rg1, rbe1, coefR1);
  if (mid) {
    conv2_stats_mfma<1><<<8192, 256, 0, stream>>>(summed, w1re, rb1, coefR1,
                                                  w2re, rb2, partialsB, h1g);
  } else {
    conv2_stats_mfma<0><<<8192, 256, 0, stream>>>(summed, w1re, rb1, coefR1,
                                                  w2re, rb2, partialsB, nullptr);
  }
  reduce_coef<<<128, 256, 0, stream>>>(partialsB, 8192, 128, rb2, rg2, rbe2, coefR2);
  if (mid) {
    conv2_final_h1<<<dim3(FGRID, NB), 256, 0, stream>>>(
        h1g, w2re, coefR2, w3g, rb3, out);
  } else {
    conv2_final_mfma<<<dim3(FGRID, NB), 256, 0, stream>>>(
        summed, w1re, rb1, coefR1, w2re, coefR2, w3g, rb3, out);
  }
}